// Round 3
// baseline (303.779 us; speedup 1.0000x reference)
//
#include <hip/hip_runtime.h>

#define HW_   (512 * 512)   // pixels per image
#define NIMG  8
#define NC    19            // classes
#define NSP   2048          // superpixels per image
#define TC    20            // target row stride (C+1, last col sliced off)
#define NROWS (NIMG * NSP)  // 16384 target rows
#define TILE  1024          // pixels per tile (4 per thread)
#define NTILE (NIMG * HW_ / TILE)   // 2048 tiles
#define NBLK  1024          // 4 blocks/CU -> ALL co-resident (spin-safe)
#define NITER (NTILE / NBLK)        // 2 tiles per block
#define NGRP  16            // completion-ticket groups (64 blocks each)
#define GSIZE (NBLK / NGRP)
#define PBLK  64            // blocks that also build the bitmask table

typedef float vf4 __attribute__((ext_vector_type(4)));
typedef int   vi4 __attribute__((ext_vector_type(4)));

// d_ws layout (first 1088 B zeroed by hipMemsetAsync each launch):
//   [0]    flag (uint)       spmask width: 1 -> 4-byte, 0 -> 1-byte
//   [4]    st   (uint)       super ticket
//   [8]    pd   (uint)       prep-done counter (0..64)
//   [64]   gt[NGRP] uints, stride 16 (64 B apart -> no same-line RMWs)
//   [1088] pl[NBLK] float    per-block loss partials
//   [5184] pc[NBLK] uint     per-block count partials
//   [9280] bmt[NROWS] uint   per-(image,superpixel) multi-hot bitmask

// ---------------------------------------------------------------------------
// Single fused kernel.
//   Phase P (blocks 0..63): coalesced-LDS bitmask build of targets (20 KB
//     staged contiguously, then per-thread row scan), device-scope release
//     on a done counter. Width detection on first 4 KB of spmask by block 1.
//   Main (all 1024 blocks): R1's 20-load dwordx4 burst per 1024-px tile,
//     now with COUNTED vmcnt chunks: vmcnt(19) frees s4 (bitmask gathers
//     issue under the stream), exp+sum chunks at vmcnt(15/11/7/3/0) hide
//     ~15us/CU of VALU + gather latency that R1 serialized after vmcnt(0).
//     Tile swizzle gives XCD-image affinity (XCD k owns a contiguous
//     half-image per iteration) AND adjacent tiles for the 4 co-resident
//     blocks per CU (shared 4-KB pages per class).
//   The prep spin sits right before the first bmt use (after the exp
//     phase), so prep cost overlaps the first burst. Grid == capacity
//     (4/CU * 256 CU) under __launch_bounds__(256,4) => no deadlock.
// Counted waits are conservative-safe: vmem retires in order, and any
// compiler-issued loads interleaving with the asm's 20 only inflate the
// outstanding count (same vmcnt N => MORE of ours retired).
// ---------------------------------------------------------------------------
__global__ __launch_bounds__(256, 4) void mcce_fused(
    const float* __restrict__ x,      // (N, C, H*W)
    const float* __restrict__ tgt,    // (N, NSP, TC)
    const int*   __restrict__ sp,     // (N, H*W)
    const void*  __restrict__ spm,    // (N, H*W) mask, 1B or 4B elements
    unsigned int* __restrict__ flag,
    unsigned int* __restrict__ st,
    unsigned int* __restrict__ pd,
    unsigned int* __restrict__ gt,
    float* __restrict__ pl, unsigned int* __restrict__ pc,
    unsigned int* __restrict__ bmt,
    float* __restrict__ out) {

    __shared__ vf4 stage[1280];        // 20 KB prep staging
    __shared__ float sL[4];
    __shared__ unsigned int sC[4];

    int b    = blockIdx.x;
    int t    = threadIdx.x;
    int wave = t >> 6;

    // ---------------- Phase P: build bitmask table ----------------
    if (b < PBLK) {
        if (b == 1 && t < 64) {        // one wave: width detection
            const unsigned int* w = (const unsigned int*)spm;
            unsigned int nonlow = 0, upper = 0;
            for (int i = t; i < 1024; i += 64) {
                unsigned int v = w[i];
                nonlow |= (v & 0xFEFEFEFEu);
                upper  |= (v & 0xFFFFFF00u);
            }
            unsigned long long b1 = __ballot(nonlow != 0);
            unsigned long long b2 = __ballot(upper != 0);
            if (t == 0)
                *flag = ((b1 == 0ull) && (b2 != 0ull)) ? 0u : 1u;
        }
        // 256 rows (20 KB) staged fully coalesced, then row scan from LDS.
        const vf4* src = (const vf4*)(tgt + (size_t)b * (256 * TC));
#pragma unroll
        for (int k = 0; k < 5; ++k) stage[t + k * 256] = src[t + k * 256];
        __syncthreads();
        const float* sf = (const float*)stage;
        unsigned int m = 0;
        int base = t * TC;
#pragma unroll
        for (int c = 0; c < NC; ++c)
            m |= (sf[base + c] != 0.0f ? 1u : 0u) << c;
        bmt[b * 256 + t] = m;
        __threadfence();               // device-scope order for bmt stores
        __syncthreads();
        if (t == 0)
            __hip_atomic_fetch_add(pd, 1u, __ATOMIC_RELEASE,
                                   __HIP_MEMORY_SCOPE_AGENT);
    }

    // ---------------- Main phase ----------------
    // tile: XCD k (=b&7) owns tiles [k*128, k*128+128) each iter (half an
    // image, 2 XCDs/image); co-resident quad {b,b+256,b+512,b+768} -> 4
    // adjacent tiles (b>>8 = low 2 bits).
    int tswz = ((b & 7) << 7) | (((b >> 3) & 31) << 2) | (b >> 8);

    float lsum = 0.0f;
    unsigned int lcnt = 0;
    unsigned int flagv = 0;

    for (int it = 0; it < NITER; ++it) {
        int T  = it * NBLK + tswz;
        int n  = T >> 8;               // 256 tiles per image
        int tp = (T & 255) * TILE;
        size_t gp = (size_t)n * HW_ + tp + 4 * t;

        const float* xb  = x  + (size_t)n * NC * HW_ + tp;
        const int*   spb = sp + (size_t)n * HW_ + tp;
        unsigned int vo  = (unsigned int)(t * 16);

        vf4 d0,d1,d2,d3,d4,d5,d6,d7,d8,d9,d10,d11,d12,d13,d14,d15,d16,d17,d18;
        vi4 s4;

        // 20 dwordx4 back-to-back; vmcnt(19) frees s4 (first issued) so the
        // bitmask gathers can issue under the remaining stream.
        asm volatile(
            "global_load_dwordx4 %[s4],  %[vo], %[spb]\n\t"
            "global_load_dwordx4 %[d0],  %[vo], %[xb]\n\t"
            "v_add_u32 %[vo], 0x100000, %[vo]\n\t"
            "global_load_dwordx4 %[d1],  %[vo], %[xb]\n\t"
            "v_add_u32 %[vo], 0x100000, %[vo]\n\t"
            "global_load_dwordx4 %[d2],  %[vo], %[xb]\n\t"
            "v_add_u32 %[vo], 0x100000, %[vo]\n\t"
            "global_load_dwordx4 %[d3],  %[vo], %[xb]\n\t"
            "v_add_u32 %[vo], 0x100000, %[vo]\n\t"
            "global_load_dwordx4 %[d4],  %[vo], %[xb]\n\t"
            "v_add_u32 %[vo], 0x100000, %[vo]\n\t"
            "global_load_dwordx4 %[d5],  %[vo], %[xb]\n\t"
            "v_add_u32 %[vo], 0x100000, %[vo]\n\t"
            "global_load_dwordx4 %[d6],  %[vo], %[xb]\n\t"
            "v_add_u32 %[vo], 0x100000, %[vo]\n\t"
            "global_load_dwordx4 %[d7],  %[vo], %[xb]\n\t"
            "v_add_u32 %[vo], 0x100000, %[vo]\n\t"
            "global_load_dwordx4 %[d8],  %[vo], %[xb]\n\t"
            "v_add_u32 %[vo], 0x100000, %[vo]\n\t"
            "global_load_dwordx4 %[d9],  %[vo], %[xb]\n\t"
            "v_add_u32 %[vo], 0x100000, %[vo]\n\t"
            "global_load_dwordx4 %[d10], %[vo], %[xb]\n\t"
            "v_add_u32 %[vo], 0x100000, %[vo]\n\t"
            "global_load_dwordx4 %[d11], %[vo], %[xb]\n\t"
            "v_add_u32 %[vo], 0x100000, %[vo]\n\t"
            "global_load_dwordx4 %[d12], %[vo], %[xb]\n\t"
            "v_add_u32 %[vo], 0x100000, %[vo]\n\t"
            "global_load_dwordx4 %[d13], %[vo], %[xb]\n\t"
            "v_add_u32 %[vo], 0x100000, %[vo]\n\t"
            "global_load_dwordx4 %[d14], %[vo], %[xb]\n\t"
            "v_add_u32 %[vo], 0x100000, %[vo]\n\t"
            "global_load_dwordx4 %[d15], %[vo], %[xb]\n\t"
            "v_add_u32 %[vo], 0x100000, %[vo]\n\t"
            "global_load_dwordx4 %[d16], %[vo], %[xb]\n\t"
            "v_add_u32 %[vo], 0x100000, %[vo]\n\t"
            "global_load_dwordx4 %[d17], %[vo], %[xb]\n\t"
            "v_add_u32 %[vo], 0x100000, %[vo]\n\t"
            "global_load_dwordx4 %[d18], %[vo], %[xb]\n\t"
            "s_waitcnt vmcnt(19)"
            : [d0]"=v"(d0), [d1]"=v"(d1), [d2]"=v"(d2), [d3]"=v"(d3),
              [d4]"=v"(d4), [d5]"=v"(d5), [d6]"=v"(d6), [d7]"=v"(d7),
              [d8]"=v"(d8), [d9]"=v"(d9), [d10]"=v"(d10), [d11]"=v"(d11),
              [d12]"=v"(d12), [d13]"=v"(d13), [d14]"=v"(d14), [d15]"=v"(d15),
              [d16]"=v"(d16), [d17]"=v"(d17), [d18]"=v"(d18),
              [s4]"=v"(s4), [vo]"+v"(vo)
            : [xb]"s"(xb), [spb]"s"(spb));

        // Bitmask gathers (L2-resident, addr from s4): issue NOW, complete
        // under the class stream; compiler's own waitcnt guards first use.
        const unsigned int* bt = bmt + n * NSP;
        unsigned int bmv0 = bt[s4.x], bmv1 = bt[s4.y],
                     bmv2 = bt[s4.z], bmv3 = bt[s4.w];

        // exp + streaming sum in ASCENDING class order (bitwise == R1),
        // chunked on counted vmcnt; register ties pin compiler ordering.
        float se[4] = {0, 0, 0, 0};
#define EXPC(R) { R.x = __expf(R.x); R.y = __expf(R.y);                        \
                  R.z = __expf(R.z); R.w = __expf(R.w);                        \
                  se[0] += R.x; se[1] += R.y; se[2] += R.z; se[3] += R.w; }
        asm volatile("s_waitcnt vmcnt(15)"
                     : "+v"(d0), "+v"(d1), "+v"(d2), "+v"(d3));
        EXPC(d0) EXPC(d1) EXPC(d2) EXPC(d3)
        asm volatile("s_waitcnt vmcnt(11)"
                     : "+v"(d4), "+v"(d5), "+v"(d6), "+v"(d7));
        EXPC(d4) EXPC(d5) EXPC(d6) EXPC(d7)
        asm volatile("s_waitcnt vmcnt(7)"
                     : "+v"(d8), "+v"(d9), "+v"(d10), "+v"(d11));
        EXPC(d8) EXPC(d9) EXPC(d10) EXPC(d11)
        asm volatile("s_waitcnt vmcnt(3)"
                     : "+v"(d12), "+v"(d13), "+v"(d14), "+v"(d15));
        EXPC(d12) EXPC(d13) EXPC(d14) EXPC(d15)
        asm volatile("s_waitcnt vmcnt(0)"
                     : "+v"(d16), "+v"(d17), "+v"(d18));
        EXPC(d16) EXPC(d17) EXPC(d18)
#undef EXPC

        // First bmt/spm use is below: wait for the prep phase exactly once.
        if (it == 0) {
            if (t == 0) {
                while (__hip_atomic_load(pd, __ATOMIC_ACQUIRE,
                                         __HIP_MEMORY_SCOPE_AGENT) < PBLK)
                    __builtin_amdgcn_s_sleep(8);
            }
            __syncthreads();
            flagv = *flag;
        }

        // Mask (wave-uniform width branch).
        int mk[4];
        if (flagv) {
            vi4 m = *(const vi4*)((const int*)spm + gp);
            mk[0] = m.x; mk[1] = m.y; mk[2] = m.z; mk[3] = m.w;
        } else {
            unsigned int mw = *(const unsigned int*)
                              ((const unsigned char*)spm + gp);
            mk[0] = mw & 0xFF;         mk[1] = (mw >> 8) & 0xFF;
            mk[2] = (mw >> 16) & 0xFF; mk[3] = (mw >> 24) & 0xFF;
        }

        // Target-sum pass, ascending class order (bitwise == R1).
        vf4 dv[NC] = {d0,d1,d2,d3,d4,d5,d6,d7,d8,d9,
                      d10,d11,d12,d13,d14,d15,d16,d17,d18};
        float ts[4] = {0, 0, 0, 0};
#pragma unroll
        for (int c = 0; c < NC; ++c) {
            ts[0] += ((bmv0 >> c) & 1) ? dv[c].x : 0.0f;
            ts[1] += ((bmv1 >> c) & 1) ? dv[c].y : 0.0f;
            ts[2] += ((bmv2 >> c) & 1) ? dv[c].z : 0.0f;
            ts[3] += ((bmv3 >> c) & 1) ? dv[c].w : 0.0f;
        }

        unsigned int bmv[4] = {bmv0, bmv1, bmv2, bmv3};
#pragma unroll
        for (int j = 0; j < 4; ++j) {
            if ((mk[j] != 0) && (bmv[j] != 0u)) {
                lsum -= __logf(ts[j] / se[j] + 1e-8f);
                ++lcnt;
            }
        }
    }

    // ---- wave-64 shuffle reduction -> LDS block reduction ----
    for (int o = 32; o > 0; o >>= 1) {
        lsum += __shfl_down(lsum, o);
        lcnt += __shfl_down(lcnt, o);
    }
    if ((t & 63) == 0) { sL[wave] = lsum; sC[wave] = lcnt; }
    __syncthreads();

    if (t == 0) {
        float        L = sL[0] + sL[1] + sL[2] + sL[3];
        unsigned int C = sC[0] + sC[1] + sC[2] + sC[3];
        __hip_atomic_store(&pl[b], L, __ATOMIC_RELAXED, __HIP_MEMORY_SCOPE_AGENT);
        __hip_atomic_store(&pc[b], C, __ATOMIC_RELAXED, __HIP_MEMORY_SCOPE_AGENT);
        // Hierarchical tickets: 16 groups of 64 (64-B-padded lines), then
        // one super ticket -> max ~64 same-line RMWs anywhere.
        unsigned int g = (unsigned int)b / GSIZE;
        unsigned int isLast = 0u;
        unsigned int tk = __hip_atomic_fetch_add(&gt[g * 16], 1u,
                              __ATOMIC_ACQ_REL, __HIP_MEMORY_SCOPE_AGENT);
        if (tk == (unsigned int)(GSIZE - 1)) {
            unsigned int s = __hip_atomic_fetch_add(st, 1u,
                                 __ATOMIC_ACQ_REL, __HIP_MEMORY_SCOPE_AGENT);
            isLast = (s == NGRP - 1) ? 1u : 0u;
        }
        sC[0] = isLast;                // reuse LDS as broadcast
    }
    __syncthreads();

    // Last block: reduce the 1024 partials and write the scalar.
    if (sC[0]) {
        float        L = 0.0f;
        unsigned int C = 0u;
        for (int i = t; i < NBLK; i += 256) {
            L += __hip_atomic_load(&pl[i], __ATOMIC_RELAXED, __HIP_MEMORY_SCOPE_AGENT);
            C += __hip_atomic_load(&pc[i], __ATOMIC_RELAXED, __HIP_MEMORY_SCOPE_AGENT);
        }
        for (int o = 32; o > 0; o >>= 1) {
            L += __shfl_down(L, o);
            C += __shfl_down(C, o);
        }
        __syncthreads();               // LDS reuse barrier
        if ((t & 63) == 0) { sL[wave] = L; sC[wave] = C; }
        __syncthreads();
        if (t == 0) {
            L = sL[0] + sL[1] + sL[2] + sL[3];
            C = sC[0] + sC[1] + sC[2] + sC[3];
            out[0] = L / (float)(1u + C);
        }
    }
}

extern "C" void kernel_launch(void* const* d_in, const int* in_sizes, int n_in,
                              void* d_out, int out_size, void* d_ws, size_t ws_size,
                              hipStream_t stream) {
    const float* x   = (const float*)d_in[0];   // inputs (8,19,512,512) f32
    const float* tgt = (const float*)d_in[1];   // targets (8,2048,20) f32
    const int*   sp  = (const int*)d_in[2];     // superpixels (8,512,512) i32
    const void*  spm = d_in[3];                 // spmasks (8,512,512), width detected

    unsigned int* flag = (unsigned int*)d_ws;
    unsigned int* st   = (unsigned int*)((char*)d_ws + 4);
    unsigned int* pd   = (unsigned int*)((char*)d_ws + 8);
    unsigned int* gt   = (unsigned int*)((char*)d_ws + 64);
    float*        pl   = (float*)((char*)d_ws + 1088);
    unsigned int* pc   = (unsigned int*)((char*)d_ws + 5184);
    unsigned int* bmt  = (unsigned int*)((char*)d_ws + 9280);

    // Zero flag/st/pd/gt (first 1088 B). Stream-ordered, graph-capturable.
    hipMemsetAsync(d_ws, 0, 1088, stream);

    mcce_fused<<<NBLK, 256, 0, stream>>>(x, tgt, sp, spm, flag, st, pd, gt,
                                         pl, pc, bmt, (float*)d_out);
}